// Round 9
// baseline (163.785 us; speedup 1.0000x reference)
//
#include <hip/hip_runtime.h>
#include <math.h>

#define N_ 8
#define C_ 256
#define P_ 784
#define K_ 64
#define F_ 16384      // K_*C_
#define FEPS 1e-12f
#define BNEPS 1e-5f
#define PBLK 25       // ceil(784/32)

__device__ __forceinline__ float wave_sum(float v) {
#pragma unroll
  for (int s = 1; s < 64; s <<= 1) v += __shfl_xor(v, s, 64);
  return v;
}
__device__ __forceinline__ float wave_max(float v) {
#pragma unroll
  for (int s = 1; s < 64; s <<= 1) v = fmaxf(v, __shfl_xor(v, s, 64));
  return v;
}

// MODE 0: production (identical math to R8). MODE 1: GEMM-only (sink).
// MODE 2: tail-only (synth acc, sink). MODE 3: GEMM w/o x-loads (sink).
// REP: inner repetition for top-5 visibility of ablation dispatches.
template <int MODE, int REP>
__global__ __launch_bounds__(512) void k_fused1_t(const float* __restrict__ x,
                                                  const float* __restrict__ convw,
                                                  const float* __restrict__ cent,
                                                  float* __restrict__ w2,
                                                  float* __restrict__ Spart) {
  __shared__ float AsT[32][136];    // [cc][kk] rows 544B
  __shared__ float G_lds[128][34];  // [kk][pp]
  __shared__ float ubuf[64 * 36];   // w2_lds[64][36]; cn2p[64][9] overlaid
  __shared__ float cn2_lds[64];
  __shared__ float ssq_ab[2][32];
  __shared__ float rinv_lds[32];
  __shared__ float xn2_lds[32];
  __shared__ float sp_lds[8][65];

  float (*w2_lds)[36] = (float(*)[36])ubuf;
  float (*cn2p)[9] = (float(*)[9])ubuf;

  const int pblk = blockIdx.x, n = blockIdx.y;
  const int p0 = pblk * 32;
  const int t = threadIdx.x;
  const int wv = t >> 6, lane = t & 63;
  const int grp = t >> 8;
  const int tl = t & 255;
  const int ty = tl >> 3;           // kk rows ty*4..+3
  const int tx = tl & 7;            // p cols {tx, tx+8, tx+16, tx+24}
  const int ccb = grp * 16;
  const float* xb = x + (size_t)n * C_ * P_;

  int pj[4];
#pragma unroll
  for (int j = 0; j < 4; ++j) {
    int p = p0 + tx + 8 * j;
    pj[j] = (p < P_) ? p : 0;
  }

  // cn2 partials + fold (hoisted pre-loop; ubuf freed for w2_lds afterwards)
  {
    int k = t >> 3, oct = t & 7;
    const float* row = cent + (size_t)k * C_ + oct * 32;
    float s = 0.f;
#pragma unroll
    for (int i = 0; i < 8; ++i) {
      float4 v = *(const float4*)&row[i * 4];
      s += v.x * v.x + v.y * v.y + v.z * v.z + v.w * v.w;
    }
    cn2p[k][oct] = s;
  }
  __syncthreads();
  if (t < 64) {
    float s = 0.f;
#pragma unroll
    for (int i = 0; i < 8; ++i) s += cn2p[t][i];
    cn2_lds[t] = s;
  }
  __syncthreads();

  const int scc = t & 31, sk = t >> 5;

  for (int rep = 0; rep < REP; ++rep) {
    float acc[4][4] = {};
    float ssqr[4] = {0.f, 0.f, 0.f, 0.f};

    if (MODE != 2) {
      // stage chunk 0
#pragma unroll
      for (int i = 0; i < 8; ++i) {
        int kk = sk * 8 + i;
        const float* Ar = (kk < 64) ? (convw + (size_t)kk * C_) : (cent + (size_t)(kk - 64) * C_);
        AsT[scc][kk] = Ar[scc];
      }
      __syncthreads();
      for (int ch = 0; ch < 8; ++ch) {
        const int c0 = ch * 32;
        float anext[8];
        if (ch < 7) {
          int c0n = c0 + 32;
#pragma unroll
          for (int i = 0; i < 8; ++i) {
            int kk = sk * 8 + i;
            const float* Ar = (kk < 64) ? (convw + (size_t)kk * C_) : (cent + (size_t)(kk - 64) * C_);
            anext[i] = Ar[c0n + scc];
          }
        }
#pragma unroll
        for (int cc = 0; cc < 16; ++cc) {
          const float* xr = xb + (size_t)(c0 + ccb + cc) * P_;
          float xv[4];
#pragma unroll
          for (int j = 0; j < 4; ++j)
            xv[j] = (MODE == 3) ? (float)(pj[j] & 31) * 0.03f : xr[pj[j]];
          float4 a = *(const float4*)&AsT[ccb + cc][ty * 4];
          if (ty == 0) {
#pragma unroll
            for (int j = 0; j < 4; ++j) ssqr[j] += xv[j] * xv[j];
          }
          float av[4] = {a.x, a.y, a.z, a.w};
#pragma unroll
          for (int i = 0; i < 4; ++i)
#pragma unroll
            for (int j = 0; j < 4; ++j) acc[i][j] += av[i] * xv[j];
        }
        __syncthreads();
        if (ch < 7) {
#pragma unroll
          for (int i = 0; i < 8; ++i) AsT[scc][sk * 8 + i] = anext[i];
          __syncthreads();
        }
      }
    } else {
      // MODE 2: synth acc (bounded values), ssq = 1
#pragma unroll
      for (int i = 0; i < 4; ++i)
#pragma unroll
        for (int j = 0; j < 4; ++j) acc[i][j] = convw[(t * 16 + i * 4 + j) & (F_ - 1)];
#pragma unroll
      for (int j = 0; j < 4; ++j) ssqr[j] = 1.f;
    }

    if (MODE == 1 || MODE == 3) {
      // sink acc + ssqr (keep GEMM live), skip tail
      float s = 0.f;
#pragma unroll
      for (int i = 0; i < 4; ++i)
#pragma unroll
        for (int j = 0; j < 4; ++j) s += acc[i][j];
#pragma unroll
      for (int j = 0; j < 4; ++j) s += ssqr[j];
      w2[(size_t)((n * PBLK + pblk) * 512 + t)] = s;
      __syncthreads();
    } else {
      // tail: G assembly, rinv/xn2, softmax, w2/Spart
      if (grp == 0) {
#pragma unroll
        for (int i = 0; i < 4; ++i)
#pragma unroll
          for (int j = 0; j < 4; ++j) G_lds[ty * 4 + i][tx + 8 * j] = acc[i][j];
      }
      if (ty == 0) {
#pragma unroll
        for (int j = 0; j < 4; ++j) ssq_ab[grp][tx + 8 * j] = ssqr[j];
      }
      __syncthreads();
      if (grp == 1) {
#pragma unroll
        for (int i = 0; i < 4; ++i)
#pragma unroll
          for (int j = 0; j < 4; ++j) G_lds[ty * 4 + i][tx + 8 * j] += acc[i][j];
      }
      __syncthreads();
      if (t < 32) {
        float s = ssq_ab[0][t] + ssq_ab[1][t];
        float r = 1.0f / fmaxf(sqrtf(s), FEPS);
        rinv_lds[t] = r;
        xn2_lds[t] = s * r * r;
      }
      __syncthreads();

      float s_acc = 0.f;
      float c2 = cn2_lds[lane];
#pragma unroll
      for (int j = 0; j < 4; ++j) {
        int pl = wv * 4 + j;
        if (p0 + pl < P_) {
          float r = rinv_lds[pl];
          float x2 = xn2_lds[pl];
          float lg = G_lds[lane][pl] * r;
          float dt = G_lds[64 + lane][pl] * r;
          float m = wave_max(lg);
          float e = expf(lg - m);
          float ssum = wave_sum(e);
          float a = e / ssum;
          float rn2 = wave_sum(a * a * (x2 - 2.f * dt + c2));
          float wf = 1.0f / fmaxf(sqrtf(rn2), FEPS);
          float wval = a * wf;
          s_acc += wval;
          w2_lds[lane][pl] = wval * r;
        }
      }
      sp_lds[wv][lane] = s_acc;
      __syncthreads();
      if (t < 64) {
        float s = 0.f;
#pragma unroll
        for (int g = 0; g < 8; ++g) s += sp_lds[g][t];
        Spart[((size_t)pblk * N_ + n) * 64 + t] = s;
      }
      {
        int k = t >> 3, q = t & 7;
        int p = p0 + q * 4;
        if (p + 3 < P_) {
          float4 v = *(const float4*)&w2_lds[k][q * 4];
          *(float4*)&w2[((size_t)n * K_ + k) * P_ + p] = v;
        }
      }
      if (REP > 1) __syncthreads();
    }
  }
}

// vpart[s][n][k][c] = sum_{p in slice s} w2[n,k,p]*x[n,c,p]
__global__ __launch_bounds__(256) void k_gemm2(const float* __restrict__ x,
                                               const float* __restrict__ w2,
                                               float* __restrict__ vpart) {
  __shared__ float WsT[32][68];
  __shared__ float XsT[32][68];
  int n = blockIdx.z, s = blockIdx.y;
  int c0 = blockIdx.x * 64;
  int t = threadIdx.x;
  int tx = t & 15, ty = t >> 4;
  float acc[4][4] = {};
  const float* wb = w2 + (size_t)n * K_ * P_;
  const float* xb = x + (size_t)n * C_ * P_;
  int pbase = s * 98;
  for (int q = 0; q < 98; q += 32) {
    int r = t >> 5, pc = t & 31;
    bool ok = (q + pc) < 98;
    int p = pbase + q + pc;
#pragma unroll
    for (int i = 0; i < 8; ++i) {
      int row = r + i * 8;
      WsT[pc][row] = ok ? wb[(size_t)row * P_ + p] : 0.f;
      XsT[pc][row] = ok ? xb[(size_t)(c0 + row) * P_ + p] : 0.f;
    }
    __syncthreads();
#pragma unroll
    for (int pp = 0; pp < 32; ++pp) {
      float4 a = *(const float4*)&WsT[pp][ty * 4];
      float4 bv = *(const float4*)&XsT[pp][tx * 4];
      float av[4] = {a.x, a.y, a.z, a.w};
      float bb[4] = {bv.x, bv.y, bv.z, bv.w};
#pragma unroll
      for (int i = 0; i < 4; ++i)
#pragma unroll
        for (int j = 0; j < 4; ++j) acc[i][j] += av[i] * bb[j];
    }
    __syncthreads();
  }
  float* vb = vpart + (size_t)(s * N_ + n) * K_ * C_;
#pragma unroll
  for (int i = 0; i < 4; ++i)
#pragma unroll
    for (int j = 0; j < 4; ++j)
      vb[(size_t)(ty * 4 + i) * C_ + c0 + tx * 4 + j] = acc[i][j];
}

__global__ __launch_bounds__(256) void k_vladnorm(const float* __restrict__ vpart,
                                                  const float* __restrict__ cent,
                                                  const float* __restrict__ Spart,
                                                  float* __restrict__ vladn) {
  __shared__ float red[4];
  int b = blockIdx.x;
  int n = b >> 6, k = b & 63;
  int c = threadIdx.x;
  float Sb = 0.f;
#pragma unroll
  for (int s = 0; s < PBLK; ++s) Sb += Spart[((size_t)s * N_ + n) * 64 + k];
  float val = 0.f;
#pragma unroll
  for (int s = 0; s < 8; ++s) val += vpart[(size_t)(s * 512 + b) * C_ + c];
  val -= cent[(size_t)k * C_ + c] * Sb;
  float ss = wave_sum(val * val);
  int wv = threadIdx.x >> 6, lane = threadIdx.x & 63;
  if (lane == 0) red[wv] = ss;
  __syncthreads();
  float tot = red[0] + red[1] + red[2] + red[3];
  float inv = 1.0f / fmaxf(sqrtf(tot), FEPS);
  vladn[(size_t)b * C_ + c] = val * inv;
}

__global__ __launch_bounds__(256) void k_bn(const float* __restrict__ vladn,
                                            const float* __restrict__ bnw,
                                            const float* __restrict__ bnb,
                                            float* __restrict__ ybuf,
                                            float* __restrict__ nrmpart) {
  __shared__ float red[4][8];
  int f = blockIdx.x * 256 + threadIdx.x;
  float v[N_];
  float s = 0.f;
#pragma unroll
  for (int n = 0; n < N_; ++n) { v[n] = vladn[(size_t)n * F_ + f]; s += v[n]; }
  float mean = s * (1.0f / N_);
  float s2 = 0.f;
#pragma unroll
  for (int n = 0; n < N_; ++n) { float d = v[n] - mean; s2 += d * d; }
  float var = s2 * (1.0f / N_);
  float sc = bnw[f] / sqrtf(var + BNEPS);
  float bb = bnb[f];
  float y[N_];
#pragma unroll
  for (int n = 0; n < N_; ++n) {
    y[n] = (v[n] - mean) * sc + bb;
    ybuf[(size_t)n * F_ + f] = y[n];
  }
  int wv = threadIdx.x >> 6, lane = threadIdx.x & 63;
#pragma unroll
  for (int n = 0; n < N_; ++n) {
    float q = wave_sum(y[n] * y[n]);
    if (lane == 0) red[wv][n] = q;
  }
  __syncthreads();
  if (threadIdx.x < N_) {
    int n = threadIdx.x;
    nrmpart[n * 64 + blockIdx.x] = red[0][n] + red[1][n] + red[2][n] + red[3][n];
  }
}

__global__ __launch_bounds__(256) void k_final(const float* __restrict__ ybuf,
                                               const float* __restrict__ nrmpart,
                                               float* __restrict__ out) {
  int idx = blockIdx.x * 256 + threadIdx.x;
  int n = idx >> 14;
  float tot = 0.f;
#pragma unroll
  for (int b = 0; b < 64; ++b) tot += nrmpart[n * 64 + b];
  float inv = 1.0f / fmaxf(sqrtf(tot), FEPS);
  out[idx] = ybuf[idx] * inv;
}

extern "C" void kernel_launch(void* const* d_in, const int* in_sizes, int n_in,
                              void* d_out, int out_size, void* d_ws, size_t ws_size,
                              hipStream_t stream) {
  const float* x = (const float*)d_in[0];
  const float* convw = (const float*)d_in[1];
  const float* cent = (const float*)d_in[2];
  const float* bnw = (const float*)d_in[3];
  const float* bnb = (const float*)d_in[4];
  float* out = (float*)d_out;
  float* ws = (float*)d_ws;

  float* Spart = ws;                // 12800
  float* nrmpart = ws + 12800;      // 512
  float* w2 = ws + 13312;           // 401408
  float* vpart = ws + 414720;       // 1048576
  float* vladn = ws + 1463296;      // 131072
  float* ybuf = ws + 1594368;       // 131072
  float* sinkw = ws + 1725440;      // 401408 (ablation sink)
  float* sinks = ws + 2126848;      // 12800  (ablation Spart sink; end ~8.6MB)

  // --- diagnostic ablations (write only to sink; run before production) ---
  k_fused1_t<1, 2><<<dim3(PBLK, N_), 512, 0, stream>>>(x, convw, cent, sinkw, sinks);
  k_fused1_t<3, 3><<<dim3(PBLK, N_), 512, 0, stream>>>(x, convw, cent, sinkw, sinks);
  k_fused1_t<2, 8><<<dim3(PBLK, N_), 512, 0, stream>>>(x, convw, cent, sinkw, sinks);

  // --- production pipeline ---
  k_fused1_t<0, 1><<<dim3(PBLK, N_), 512, 0, stream>>>(x, convw, cent, w2, Spart);
  k_gemm2<<<dim3(4, 8, 8), 256, 0, stream>>>(x, w2, vpart);
  k_vladnorm<<<512, 256, 0, stream>>>(vpart, cent, Spart, vladn);
  k_bn<<<64, 256, 0, stream>>>(vladn, bnw, bnb, ybuf, nrmpart);
  k_final<<<512, 256, 0, stream>>>(ybuf, nrmpart, out);
}

// Round 10
// 93.467 us; speedup vs baseline: 1.7523x; 1.7523x over previous
//
#include <hip/hip_runtime.h>
#include <math.h>

#define N_ 8
#define C_ 256
#define P_ 784
#define K_ 64
#define F_ 16384      // K_*C_
#define FEPS 1e-12f
#define BNEPS 1e-5f
#define PBLK 13       // ceil(784/64)

__device__ __forceinline__ float wave_sum(float v) {
#pragma unroll
  for (int s = 1; s < 64; s <<= 1) v += __shfl_xor(v, s, 64);
  return v;
}
__device__ __forceinline__ float wave_max(float v) {
#pragma unroll
  for (int s = 1; s < 64; s <<= 1) v = fmaxf(v, __shfl_xor(v, s, 64));
  return v;
}

// Fused GEMM+softmax, scalar-broadcast A structure:
//   lane = p (64 positions/tile), wave = 8 kk rows (16 waves = 128 kk).
//   A[kk][cc] wave-uniform -> SGPR via readfirstlane'd wave id; x per-lane
//   coalesced global loads (L1-resident slab), prefetched 1 chunk ahead.
//   No LDS, no barriers in the GEMM loop; 3 barriers total.
// grid (13, 8), 1024 threads.
__global__ __launch_bounds__(1024) void k_fused1(const float* __restrict__ x,
                                                 const float* __restrict__ convw,
                                                 const float* __restrict__ cent,
                                                 float* __restrict__ w2,
                                                 float* __restrict__ Spart) {
  __shared__ float G_lds[64][133];   // [p][kk] pad133: 2 lanes/bank on write
  __shared__ float w2u[64 * 68];     // w2_lds[64][68]; cn2p[64][9] overlay (pre-GEMM only)
  __shared__ float cn2_lds[64];
  __shared__ float rinv_lds[64];
  __shared__ float xn2_lds[64];
  __shared__ float sp_lds[16][65];

  float (*w2_lds)[68] = (float(*)[68])w2u;
  float (*cn2p)[9] = (float(*)[9])w2u;

  const int pblk = blockIdx.x, n = blockIdx.y;
  const int p0 = pblk * 64;
  const int t = threadIdx.x;
  const int lane = t & 63;
  const int wid = __builtin_amdgcn_readfirstlane(t >> 6);  // 0..15, SGPR
  const float* xb = x + (size_t)n * C_ * P_;
  const int myp = p0 + lane;
  const int xp = (myp < P_) ? myp : (P_ - 1);  // clamp; junk rows never read

  // cn2 partials (512 threads), fold to cn2_lds
  if (t < 512) {
    int k = t >> 3, oct = t & 7;
    const float* row = cent + (size_t)k * C_ + oct * 32;
    float s = 0.f;
#pragma unroll
    for (int i = 0; i < 8; ++i) {
      float4 v = *(const float4*)&row[i * 4];
      s += v.x * v.x + v.y * v.y + v.z * v.z + v.w * v.w;
    }
    cn2p[k][oct] = s;
  }
  __syncthreads();
  if (t < 64) {
    float s = 0.f;
#pragma unroll
    for (int i = 0; i < 8; ++i) s += cn2p[t][i];
    cn2_lds[t] = s;
  }

  // wave-uniform A row base: waves 0-7 -> convw rows, 8-15 -> cent rows
  const float* Arow = (wid < 8) ? (convw + (size_t)(wid * 8) * C_)
                                : (cent + (size_t)(wid * 8 - 64) * C_);

  float acc[8] = {0.f, 0.f, 0.f, 0.f, 0.f, 0.f, 0.f, 0.f};
  float ssq = 0.f;
  float xcur[32], xnxt[32];
#pragma unroll
  for (int cc = 0; cc < 32; ++cc) xcur[cc] = xb[(size_t)cc * P_ + xp];

  for (int ch = 0; ch < 8; ++ch) {
    const int c0 = ch * 32;
    if (ch < 7) {
#pragma unroll
      for (int cc = 0; cc < 32; ++cc) xnxt[cc] = xb[(size_t)(c0 + 32 + cc) * P_ + xp];
    }
    if (wid == 0) {   // wave-uniform predicate: only wave 0 pays for ssq
#pragma unroll
      for (int cc = 0; cc < 32; ++cc) ssq = fmaf(xcur[cc], xcur[cc], ssq);
    }
    // A in 4-cc slices: 8x4 wave-uniform scalars feed 32 broadcast FMAs each
#pragma unroll
    for (int sl = 0; sl < 8; ++sl) {
      float as[8][4];
#pragma unroll
      for (int i = 0; i < 8; ++i)
#pragma unroll
        for (int q = 0; q < 4; ++q)
          as[i][q] = Arow[(size_t)i * C_ + c0 + sl * 4 + q];
#pragma unroll
      for (int q = 0; q < 4; ++q)
#pragma unroll
        for (int i = 0; i < 8; ++i)
          acc[i] = fmaf(as[i][q], xcur[sl * 4 + q], acc[i]);
    }
    if (ch < 7) {
#pragma unroll
      for (int cc = 0; cc < 32; ++cc) xcur[cc] = xnxt[cc];
    }
  }

  // G -> LDS [p][kk]; rinv/xn2 direct from wave-0 registers (no reduction)
#pragma unroll
  for (int i = 0; i < 8; ++i) G_lds[lane][wid * 8 + i] = acc[i];
  if (wid == 0) {
    float r = 1.0f / fmaxf(sqrtf(ssq), FEPS);
    rinv_lds[lane] = r;
    xn2_lds[lane] = ssq * r * r;
  }
  __syncthreads();

  // softmax / rn / w2: wave wid handles pl = wid*4 + j; lane = k
  float s_acc = 0.f;
  float c2 = cn2_lds[lane];
#pragma unroll
  for (int j = 0; j < 4; ++j) {
    int pl = wid * 4 + j;
    if (p0 + pl < P_) {   // wave-uniform
      float r = rinv_lds[pl];
      float x2 = xn2_lds[pl];
      float lg = G_lds[pl][lane] * r;
      float dt = G_lds[pl][64 + lane] * r;
      float m = wave_max(lg);
      float e = expf(lg - m);
      float ssum = wave_sum(e);
      float a = e / ssum;
      float rn2 = wave_sum(a * a * (x2 - 2.f * dt + c2));
      float wf = 1.0f / fmaxf(sqrtf(rn2), FEPS);
      float wval = a * wf;
      s_acc += wval;
      w2_lds[lane][pl] = wval * r;
    }
  }
  sp_lds[wid][lane] = s_acc;
  __syncthreads();
  if (t < 64) {
    float s = 0.f;
#pragma unroll
    for (int g = 0; g < 16; ++g) s += sp_lds[g][t];
    Spart[((size_t)pblk * N_ + n) * 64 + t] = s;
  }
  // w2 writeout: t -> k = t>>4, q = t&15: float4 at p0+q*4
  {
    int k = t >> 4, q = t & 15;
    int p = p0 + q * 4;
    if (p + 3 < P_) {
      float4 v = *(const float4*)&w2_lds[k][q * 4];
      *(float4*)&w2[((size_t)n * K_ + k) * P_ + p] = v;
    }
  }
}

// vpart[s][n][k][c] = sum_{p in slice s} w2[n,k,p]*x[n,c,p]
// grid (4 c-tiles, 8 splits, 8 n) = 256 blocks, 4 p-chunks each.
__global__ __launch_bounds__(256) void k_gemm2(const float* __restrict__ x,
                                               const float* __restrict__ w2,
                                               float* __restrict__ vpart) {
  __shared__ float WsT[32][68];
  __shared__ float XsT[32][68];
  int n = blockIdx.z, s = blockIdx.y;
  int c0 = blockIdx.x * 64;
  int t = threadIdx.x;
  int tx = t & 15, ty = t >> 4;
  float acc[4][4] = {};
  const float* wb = w2 + (size_t)n * K_ * P_;
  const float* xb = x + (size_t)n * C_ * P_;
  int pbase = s * 98;
  for (int q = 0; q < 98; q += 32) {
    int r = t >> 5, pc = t & 31;
    bool ok = (q + pc) < 98;
    int p = pbase + q + pc;
#pragma unroll
    for (int i = 0; i < 8; ++i) {
      int row = r + i * 8;
      WsT[pc][row] = ok ? wb[(size_t)row * P_ + p] : 0.f;
      XsT[pc][row] = ok ? xb[(size_t)(c0 + row) * P_ + p] : 0.f;
    }
    __syncthreads();
#pragma unroll
    for (int pp = 0; pp < 32; ++pp) {
      float4 a = *(const float4*)&WsT[pp][ty * 4];
      float4 bv = *(const float4*)&XsT[pp][tx * 4];
      float av[4] = {a.x, a.y, a.z, a.w};
      float bb[4] = {bv.x, bv.y, bv.z, bv.w};
#pragma unroll
      for (int i = 0; i < 4; ++i)
#pragma unroll
        for (int j = 0; j < 4; ++j) acc[i][j] += av[i] * bb[j];
    }
    __syncthreads();
  }
  float* vb = vpart + (size_t)(s * N_ + n) * K_ * C_;
#pragma unroll
  for (int i = 0; i < 4; ++i)
#pragma unroll
    for (int j = 0; j < 4; ++j)
      vb[(size_t)(ty * 4 + i) * C_ + c0 + tx * 4 + j] = acc[i][j];
}

// vladn[n,k,c] = (sum_s vpart - cent*sum_s Spart) / max(||.||_c, eps). grid 512
__global__ __launch_bounds__(256) void k_vladnorm(const float* __restrict__ vpart,
                                                  const float* __restrict__ cent,
                                                  const float* __restrict__ Spart,
                                                  float* __restrict__ vladn) {
  __shared__ float red[4];
  int b = blockIdx.x;
  int n = b >> 6, k = b & 63;
  int c = threadIdx.x;
  float Sb = 0.f;
#pragma unroll
  for (int s = 0; s < PBLK; ++s) Sb += Spart[((size_t)s * N_ + n) * 64 + k];
  float val = 0.f;
#pragma unroll
  for (int s = 0; s < 8; ++s) val += vpart[(size_t)(s * 512 + b) * C_ + c];
  val -= cent[(size_t)k * C_ + c] * Sb;
  float ss = wave_sum(val * val);
  int wv = threadIdx.x >> 6, lane = threadIdx.x & 63;
  if (lane == 0) red[wv] = ss;
  __syncthreads();
  float tot = red[0] + red[1] + red[2] + red[3];
  float inv = 1.0f / fmaxf(sqrtf(tot), FEPS);
  vladn[(size_t)b * C_ + c] = val * inv;
}

// BatchNorm over n (biased var) + bn affine; per-block partial ssq into nrmpart.
__global__ __launch_bounds__(256) void k_bn(const float* __restrict__ vladn,
                                            const float* __restrict__ bnw,
                                            const float* __restrict__ bnb,
                                            float* __restrict__ ybuf,
                                            float* __restrict__ nrmpart) {
  __shared__ float red[4][8];
  int f = blockIdx.x * 256 + threadIdx.x;
  float v[N_];
  float s = 0.f;
#pragma unroll
  for (int n = 0; n < N_; ++n) { v[n] = vladn[(size_t)n * F_ + f]; s += v[n]; }
  float mean = s * (1.0f / N_);
  float s2 = 0.f;
#pragma unroll
  for (int n = 0; n < N_; ++n) { float d = v[n] - mean; s2 += d * d; }
  float var = s2 * (1.0f / N_);
  float sc = bnw[f] / sqrtf(var + BNEPS);
  float bb = bnb[f];
  float y[N_];
#pragma unroll
  for (int n = 0; n < N_; ++n) {
    y[n] = (v[n] - mean) * sc + bb;
    ybuf[(size_t)n * F_ + f] = y[n];
  }
  int wv = threadIdx.x >> 6, lane = threadIdx.x & 63;
#pragma unroll
  for (int n = 0; n < N_; ++n) {
    float q = wave_sum(y[n] * y[n]);
    if (lane == 0) red[wv][n] = q;
  }
  __syncthreads();
  if (threadIdx.x < N_) {
    int n = threadIdx.x;
    nrmpart[n * 64 + blockIdx.x] = red[0][n] + red[1][n] + red[2][n] + red[3][n];
  }
}

// out = y / max(||y_n||, eps). grid 512.
__global__ __launch_bounds__(256) void k_final(const float* __restrict__ ybuf,
                                               const float* __restrict__ nrmpart,
                                               float* __restrict__ out) {
  int idx = blockIdx.x * 256 + threadIdx.x;
  int n = idx >> 14;
  float tot = 0.f;
#pragma unroll
  for (int b = 0; b < 64; ++b) tot += nrmpart[n * 64 + b];
  float inv = 1.0f / fmaxf(sqrtf(tot), FEPS);
  out[idx] = ybuf[idx] * inv;
}

extern "C" void kernel_launch(void* const* d_in, const int* in_sizes, int n_in,
                              void* d_out, int out_size, void* d_ws, size_t ws_size,
                              hipStream_t stream) {
  const float* x = (const float*)d_in[0];
  const float* convw = (const float*)d_in[1];
  const float* cent = (const float*)d_in[2];
  const float* bnw = (const float*)d_in[3];
  const float* bnb = (const float*)d_in[4];
  float* out = (float*)d_out;
  float* ws = (float*)d_ws;

  float* Spart = ws;                // 13*8*64 = 6656
  float* nrmpart = ws + 6656;       // 512
  float* w2 = ws + 7168;            // 8*64*784 = 401408
  float* vpart = ws + 408576;       // 8*512*256 = 1048576
  float* vladn = ws + 1457152;      // 131072
  float* ybuf = ws + 1588224;       // 131072  (end ~6.9MB)

  k_fused1<<<dim3(PBLK, N_), 1024, 0, stream>>>(x, convw, cent, w2, Spart);
  k_gemm2<<<dim3(4, 8, 8), 256, 0, stream>>>(x, w2, vpart);
  k_vladnorm<<<512, 256, 0, stream>>>(vpart, cent, Spart, vladn);
  k_bn<<<64, 256, 0, stream>>>(vladn, bnw, bnb, ybuf, nrmpart);
  k_final<<<512, 256, 0, stream>>>(ybuf, nrmpart, out);
}

// Round 11
// 61.907 us; speedup vs baseline: 2.6456x; 1.5098x over previous
//
#include <hip/hip_runtime.h>
#include <math.h>

#define N_ 8
#define C_ 256
#define P_ 784
#define K_ 64
#define F_ 16384      // K_*C_
#define FEPS 1e-12f
#define BNEPS 1e-5f
#define PBLK 13       // ceil(784/64)

__device__ __forceinline__ float wave_sum(float v) {
#pragma unroll
  for (int s = 1; s < 64; s <<= 1) v += __shfl_xor(v, s, 64);
  return v;
}
__device__ __forceinline__ float wave_max(float v) {
#pragma unroll
  for (int s = 1; s < 64; s <<= 1) v = fmaxf(v, __shfl_xor(v, s, 64));
  return v;
}

// Fused GEMM+softmax, scalar-broadcast A structure:
//   lane = p (64 positions/tile), wave = 8 kk rows (16 waves = 128 kk).
//   A[kk][cc] wave-uniform -> scalar loads; x per-lane coalesced (L1-hit),
//   16-cc window prefetched 1 chunk ahead. No LDS/barriers in GEMM loop.
// grid (13, 8), 1024 threads. launch_bounds(1024,4): 128-VGPR cap, no spill
// (register core = xcur16 + xnxt16 + acc8 = 40).
__global__ __launch_bounds__(1024, 4) void k_fused1(const float* __restrict__ x,
                                                    const float* __restrict__ convw,
                                                    const float* __restrict__ cent,
                                                    float* __restrict__ w2,
                                                    float* __restrict__ Spart) {
  __shared__ float G_lds[64][133];   // [p][kk] pad133: 2 lanes/bank on write
  __shared__ float w2u[64 * 68];     // w2_lds[64][68]; cn2p[64][9] overlay (pre-GEMM only)
  __shared__ float cn2_lds[64];
  __shared__ float rinv_lds[64];
  __shared__ float xn2_lds[64];
  __shared__ float sp_lds[16][65];

  float (*w2_lds)[68] = (float(*)[68])w2u;
  float (*cn2p)[9] = (float(*)[9])w2u;

  const int pblk = blockIdx.x, n = blockIdx.y;
  const int p0 = pblk * 64;
  const int t = threadIdx.x;
  const int lane = t & 63;
  const int wid = __builtin_amdgcn_readfirstlane(t >> 6);  // 0..15, SGPR
  const float* xb = x + (size_t)n * C_ * P_;
  const int myp = p0 + lane;
  const int xp = (myp < P_) ? myp : (P_ - 1);  // clamp; junk rows never read

  // cn2 partials (512 threads), fold to cn2_lds
  if (t < 512) {
    int k = t >> 3, oct = t & 7;
    const float* row = cent + (size_t)k * C_ + oct * 32;
    float s = 0.f;
#pragma unroll
    for (int i = 0; i < 8; ++i) {
      float4 v = *(const float4*)&row[i * 4];
      s += v.x * v.x + v.y * v.y + v.z * v.z + v.w * v.w;
    }
    cn2p[k][oct] = s;
  }
  __syncthreads();
  if (t < 64) {
    float s = 0.f;
#pragma unroll
    for (int i = 0; i < 8; ++i) s += cn2p[t][i];
    cn2_lds[t] = s;
  }

  // wave-uniform A row base: waves 0-7 -> convw rows, 8-15 -> cent rows
  const float* Arow = (wid < 8) ? (convw + (size_t)(wid * 8) * C_)
                                : (cent + (size_t)(wid * 8 - 64) * C_);

  float acc[8] = {0.f, 0.f, 0.f, 0.f, 0.f, 0.f, 0.f, 0.f};
  float ssq = 0.f;
  float xcur[16], xnxt[16];
#pragma unroll
  for (int cc = 0; cc < 16; ++cc) xcur[cc] = xb[(size_t)cc * P_ + xp];

  for (int ch = 0; ch < 16; ++ch) {
    const int c0 = ch * 16;
    if (ch < 15) {
#pragma unroll
      for (int cc = 0; cc < 16; ++cc) xnxt[cc] = xb[(size_t)(c0 + 16 + cc) * P_ + xp];
    }
    if (wid == 0) {   // scalar branch (wid is SGPR): only wave 0 pays for ssq
#pragma unroll
      for (int cc = 0; cc < 16; ++cc) ssq = fmaf(xcur[cc], xcur[cc], ssq);
    }
    // A in 4-cc slices: 8x4 wave-uniform scalars feed broadcast FMAs
#pragma unroll
    for (int sl = 0; sl < 4; ++sl) {
      float as[8][4];
#pragma unroll
      for (int i = 0; i < 8; ++i)
#pragma unroll
        for (int q = 0; q < 4; ++q)
          as[i][q] = Arow[(size_t)i * C_ + c0 + sl * 4 + q];
#pragma unroll
      for (int q = 0; q < 4; ++q)
#pragma unroll
        for (int i = 0; i < 8; ++i)
          acc[i] = fmaf(as[i][q], xcur[sl * 4 + q], acc[i]);
    }
    if (ch < 15) {
#pragma unroll
      for (int cc = 0; cc < 16; ++cc) xcur[cc] = xnxt[cc];
    }
  }

  // G -> LDS [p][kk]; rinv/xn2 direct from wave-0 registers (no reduction)
#pragma unroll
  for (int i = 0; i < 8; ++i) G_lds[lane][wid * 8 + i] = acc[i];
  if (wid == 0) {
    float r = 1.0f / fmaxf(sqrtf(ssq), FEPS);
    rinv_lds[lane] = r;
    xn2_lds[lane] = ssq * r * r;
  }
  __syncthreads();

  // softmax / rn / w2: wave wid handles pl = wid*4 + j; lane = k
  float s_acc = 0.f;
  float c2 = cn2_lds[lane];
#pragma unroll
  for (int j = 0; j < 4; ++j) {
    int pl = wid * 4 + j;
    if (p0 + pl < P_) {   // wave-uniform
      float r = rinv_lds[pl];
      float x2 = xn2_lds[pl];
      float lg = G_lds[pl][lane] * r;
      float dt = G_lds[pl][64 + lane] * r;
      float m = wave_max(lg);
      float e = expf(lg - m);
      float ssum = wave_sum(e);
      float a = e / ssum;
      float rn2 = wave_sum(a * a * (x2 - 2.f * dt + c2));
      float wf = 1.0f / fmaxf(sqrtf(rn2), FEPS);
      float wval = a * wf;
      s_acc += wval;
      w2_lds[lane][pl] = wval * r;
    }
  }
  sp_lds[wid][lane] = s_acc;
  __syncthreads();
  if (t < 64) {
    float s = 0.f;
#pragma unroll
    for (int g = 0; g < 16; ++g) s += sp_lds[g][t];
    Spart[((size_t)pblk * N_ + n) * 64 + t] = s;
  }
  // w2 writeout: t -> k = t>>4, q = t&15: float4 at p0+q*4
  {
    int k = t >> 4, q = t & 15;
    int p = p0 + q * 4;
    if (p + 3 < P_) {
      float4 v = *(const float4*)&w2_lds[k][q * 4];
      *(float4*)&w2[((size_t)n * K_ + k) * P_ + p] = v;
    }
  }
}

// vpart[s][n][k][c] = sum_{p in slice s} w2[n,k,p]*x[n,c,p]
// grid (4 c-tiles, 8 splits, 8 n) = 256 blocks, 4 p-chunks each.
__global__ __launch_bounds__(256) void k_gemm2(const float* __restrict__ x,
                                               const float* __restrict__ w2,
                                               float* __restrict__ vpart) {
  __shared__ float WsT[32][68];
  __shared__ float XsT[32][68];
  int n = blockIdx.z, s = blockIdx.y;
  int c0 = blockIdx.x * 64;
  int t = threadIdx.x;
  int tx = t & 15, ty = t >> 4;
  float acc[4][4] = {};
  const float* wb = w2 + (size_t)n * K_ * P_;
  const float* xb = x + (size_t)n * C_ * P_;
  int pbase = s * 98;
  for (int q = 0; q < 98; q += 32) {
    int r = t >> 5, pc = t & 31;
    bool ok = (q + pc) < 98;
    int p = pbase + q + pc;
#pragma unroll
    for (int i = 0; i < 8; ++i) {
      int row = r + i * 8;
      WsT[pc][row] = ok ? wb[(size_t)row * P_ + p] : 0.f;
      XsT[pc][row] = ok ? xb[(size_t)(c0 + row) * P_ + p] : 0.f;
    }
    __syncthreads();
#pragma unroll
    for (int pp = 0; pp < 32; ++pp) {
      float4 a = *(const float4*)&WsT[pp][ty * 4];
      float4 bv = *(const float4*)&XsT[pp][tx * 4];
      float av[4] = {a.x, a.y, a.z, a.w};
      float bb[4] = {bv.x, bv.y, bv.z, bv.w};
#pragma unroll
      for (int i = 0; i < 4; ++i)
#pragma unroll
        for (int j = 0; j < 4; ++j) acc[i][j] += av[i] * bb[j];
    }
    __syncthreads();
  }
  float* vb = vpart + (size_t)(s * N_ + n) * K_ * C_;
#pragma unroll
  for (int i = 0; i < 4; ++i)
#pragma unroll
    for (int j = 0; j < 4; ++j)
      vb[(size_t)(ty * 4 + i) * C_ + c0 + tx * 4 + j] = acc[i][j];
}

// vladn[n,k,c] = (sum_s vpart - cent*sum_s Spart) / max(||.||_c, eps). grid 512
__global__ __launch_bounds__(256) void k_vladnorm(const float* __restrict__ vpart,
                                                  const float* __restrict__ cent,
                                                  const float* __restrict__ Spart,
                                                  float* __restrict__ vladn) {
  __shared__ float red[4];
  int b = blockIdx.x;
  int n = b >> 6, k = b & 63;
  int c = threadIdx.x;
  float Sb = 0.f;
#pragma unroll
  for (int s = 0; s < PBLK; ++s) Sb += Spart[((size_t)s * N_ + n) * 64 + k];
  float val = 0.f;
#pragma unroll
  for (int s = 0; s < 8; ++s) val += vpart[(size_t)(s * 512 + b) * C_ + c];
  val -= cent[(size_t)k * C_ + c] * Sb;
  float ss = wave_sum(val * val);
  int wv = threadIdx.x >> 6, lane = threadIdx.x & 63;
  if (lane == 0) red[wv] = ss;
  __syncthreads();
  float tot = red[0] + red[1] + red[2] + red[3];
  float inv = 1.0f / fmaxf(sqrtf(tot), FEPS);
  vladn[(size_t)b * C_ + c] = val * inv;
}

// BatchNorm over n (biased var) + bn affine; per-block partial ssq into nrmpart.
__global__ __launch_bounds__(256) void k_bn(const float* __restrict__ vladn,
                                            const float* __restrict__ bnw,
                                            const float* __restrict__ bnb,
                                            float* __restrict__ ybuf,
                                            float* __restrict__ nrmpart) {
  __shared__ float red[4][8];
  int f = blockIdx.x * 256 + threadIdx.x;
  float v[N_];
  float s = 0.f;
#pragma unroll
  for (int n = 0; n < N_; ++n) { v[n] = vladn[(size_t)n * F_ + f]; s += v[n]; }
  float mean = s * (1.0f / N_);
  float s2 = 0.f;
#pragma unroll
  for (int n = 0; n < N_; ++n) { float d = v[n] - mean; s2 += d * d; }
  float var = s2 * (1.0f / N_);
  float sc = bnw[f] / sqrtf(var + BNEPS);
  float bb = bnb[f];
  float y[N_];
#pragma unroll
  for (int n = 0; n < N_; ++n) {
    y[n] = (v[n] - mean) * sc + bb;
    ybuf[(size_t)n * F_ + f] = y[n];
  }
  int wv = threadIdx.x >> 6, lane = threadIdx.x & 63;
#pragma unroll
  for (int n = 0; n < N_; ++n) {
    float q = wave_sum(y[n] * y[n]);
    if (lane == 0) red[wv][n] = q;
  }
  __syncthreads();
  if (threadIdx.x < N_) {
    int n = threadIdx.x;
    nrmpart[n * 64 + blockIdx.x] = red[0][n] + red[1][n] + red[2][n] + red[3][n];
  }
}

// out = y / max(||y_n||, eps). grid 512.
__global__ __launch_bounds__(256) void k_final(const float* __restrict__ ybuf,
                                               const float* __restrict__ nrmpart,
                                               float* __restrict__ out) {
  int idx = blockIdx.x * 256 + threadIdx.x;
  int n = idx >> 14;
  float tot = 0.f;
#pragma unroll
  for (int b = 0; b < 64; ++b) tot += nrmpart[n * 64 + b];
  float inv = 1.0f / fmaxf(sqrtf(tot), FEPS);
  out[idx] = ybuf[idx] * inv;
}

extern "C" void kernel_launch(void* const* d_in, const int* in_sizes, int n_in,
                              void* d_out, int out_size, void* d_ws, size_t ws_size,
                              hipStream_t stream) {
  const float* x = (const float*)d_in[0];
  const float* convw = (const float*)d_in[1];
  const float* cent = (const float*)d_in[2];
  const float* bnw = (const float*)d_in[3];
  const float* bnb = (const float*)d_in[4];
  float* out = (float*)d_out;
  float* ws = (float*)d_ws;

  float* Spart = ws;                // 13*8*64 = 6656
  float* nrmpart = ws + 6656;       // 512
  float* w2 = ws + 7168;            // 8*64*784 = 401408
  float* vpart = ws + 408576;       // 8*512*256 = 1048576
  float* vladn = ws + 1457152;      // 131072
  float* ybuf = ws + 1588224;       // 131072  (end ~6.9MB)

  k_fused1<<<dim3(PBLK, N_), 1024, 0, stream>>>(x, convw, cent, w2, Spart);
  k_gemm2<<<dim3(4, 8, 8), 256, 0, stream>>>(x, w2, vpart);
  k_vladnorm<<<512, 256, 0, stream>>>(vpart, cent, Spart, vladn);
  k_bn<<<64, 256, 0, stream>>>(vladn, bnw, bnb, ybuf, nrmpart);
  k_final<<<512, 256, 0, stream>>>(ybuf, nrmpart, out);
}

// Round 12
// 61.269 us; speedup vs baseline: 2.6732x; 1.0104x over previous
//
#include <hip/hip_runtime.h>
#include <math.h>

#define N_ 8
#define C_ 256
#define P_ 784
#define K_ 64
#define F_ 16384      // K_*C_
#define FEPS 1e-12f
#define BNEPS 1e-5f
#define PBLK 13       // ceil(784/64)

__device__ __forceinline__ float wave_sum(float v) {
#pragma unroll
  for (int s = 1; s < 64; s <<= 1) v += __shfl_xor(v, s, 64);
  return v;
}
__device__ __forceinline__ float wave_max(float v) {
#pragma unroll
  for (int s = 1; s < 64; s <<= 1) v = fmaxf(v, __shfl_xor(v, s, 64));
  return v;
}

// Fused GEMM+softmax, scalar-broadcast A:
//   lane = p (64/tile), wave = 8 kk rows (16 waves = 128 kk).
//   A fetched as wave-uniform float4 pairs (s_load_dwordx4/x8, ~16 SMEM
//   instrs per chunk per wave vs 128 scalar dwords in R11 -- the R11 wall).
//   x per-lane coalesced, 16-cc window prefetched 1 chunk ahead.
// grid (13, 8), 1024 threads, launch_bounds(1024,4): VGPR<=128, no spill.
__global__ __launch_bounds__(1024, 4) void k_fused1(const float* __restrict__ x,
                                                    const float* __restrict__ convw,
                                                    const float* __restrict__ cent,
                                                    float* __restrict__ w2,
                                                    float* __restrict__ Spart) {
  __shared__ float G_lds[64][133];   // [p][kk] stride 133: 2 lanes/bank on write
  __shared__ float w2u[64 * 68];     // w2_lds[64][68]; cn2p[64][9] overlay (pre-GEMM only)
  __shared__ float cn2_lds[64];
  __shared__ float rinv_lds[64];
  __shared__ float xn2_lds[64];
  __shared__ float sp_lds[16][65];

  float (*w2_lds)[68] = (float(*)[68])w2u;
  float (*cn2p)[9] = (float(*)[9])w2u;

  const int pblk = blockIdx.x, n = blockIdx.y;
  const int p0 = pblk * 64;
  const int t = threadIdx.x;
  const int lane = t & 63;
  const int wid = __builtin_amdgcn_readfirstlane(t >> 6);  // 0..15, SGPR
  const float* xb = x + (size_t)n * C_ * P_;
  const int myp = p0 + lane;
  const int xp = (myp < P_) ? myp : (P_ - 1);  // clamp; junk rows never read

  // cn2 partials (512 threads), fold to cn2_lds
  if (t < 512) {
    int k = t >> 3, oct = t & 7;
    const float* row = cent + (size_t)k * C_ + oct * 32;
    float s = 0.f;
#pragma unroll
    for (int i = 0; i < 8; ++i) {
      float4 v = *(const float4*)&row[i * 4];
      s += v.x * v.x + v.y * v.y + v.z * v.z + v.w * v.w;
    }
    cn2p[k][oct] = s;
  }
  __syncthreads();
  if (t < 64) {
    float s = 0.f;
#pragma unroll
    for (int i = 0; i < 8; ++i) s += cn2p[t][i];
    cn2_lds[t] = s;
  }

  // wave-uniform A row base: waves 0-7 -> convw rows, 8-15 -> cent rows
  const float* Arow = (wid < 8) ? (convw + (size_t)(wid * 8) * C_)
                                : (cent + (size_t)(wid * 8 - 64) * C_);

  float acc[8] = {0.f, 0.f, 0.f, 0.f, 0.f, 0.f, 0.f, 0.f};
  float ssq = 0.f;
  float xcur[16], xnxt[16];
#pragma unroll
  for (int cc = 0; cc < 16; ++cc) xcur[cc] = xb[(size_t)cc * P_ + xp];

  for (int ch = 0; ch < 16; ++ch) {
    const int c0 = ch * 16;
    if (ch < 15) {
#pragma unroll
      for (int cc = 0; cc < 16; ++cc) xnxt[cc] = xb[(size_t)(c0 + 16 + cc) * P_ + xp];
    }
    if (wid == 0) {   // scalar branch (wid is SGPR): only wave 0 pays for ssq
#pragma unroll
      for (int cc = 0; cc < 16; ++cc) ssq = fmaf(xcur[cc], xcur[cc], ssq);
    }
    // A per half-chunk: 8 rows x 2 adjacent float4 (uniform -> s_load_dwordx4,
    // adjacent pairs mergeable to dwordx8). 64 FMAs per half-chunk.
#pragma unroll
    for (int hc = 0; hc < 2; ++hc) {
      float4 as4[8][2];
#pragma unroll
      for (int i = 0; i < 8; ++i) {
        as4[i][0] = *(const float4*)&Arow[(size_t)i * C_ + c0 + hc * 8];
        as4[i][1] = *(const float4*)&Arow[(size_t)i * C_ + c0 + hc * 8 + 4];
      }
#pragma unroll
      for (int h = 0; h < 2; ++h) {
        float xq0 = xcur[hc * 8 + h * 4 + 0];
        float xq1 = xcur[hc * 8 + h * 4 + 1];
        float xq2 = xcur[hc * 8 + h * 4 + 2];
        float xq3 = xcur[hc * 8 + h * 4 + 3];
#pragma unroll
        for (int i = 0; i < 8; ++i) {
          acc[i] = fmaf(as4[i][h].x, xq0, acc[i]);
          acc[i] = fmaf(as4[i][h].y, xq1, acc[i]);
          acc[i] = fmaf(as4[i][h].z, xq2, acc[i]);
          acc[i] = fmaf(as4[i][h].w, xq3, acc[i]);
        }
      }
    }
    if (ch < 15) {
#pragma unroll
      for (int cc = 0; cc < 16; ++cc) xcur[cc] = xnxt[cc];
    }
  }

  // G -> LDS [p][kk]; rinv/xn2 direct from wave-0 registers (no reduction)
#pragma unroll
  for (int i = 0; i < 8; ++i) G_lds[lane][wid * 8 + i] = acc[i];
  if (wid == 0) {
    float r = 1.0f / fmaxf(sqrtf(ssq), FEPS);
    rinv_lds[lane] = r;
    xn2_lds[lane] = ssq * r * r;
  }
  __syncthreads();

  // softmax / rn / w2: wave wid handles pl = wid*4 + j; lane = k
  float s_acc = 0.f;
  float c2 = cn2_lds[lane];
#pragma unroll
  for (int j = 0; j < 4; ++j) {
    int pl = wid * 4 + j;
    if (p0 + pl < P_) {   // wave-uniform
      float r = rinv_lds[pl];
      float x2 = xn2_lds[pl];
      float lg = G_lds[pl][lane] * r;
      float dt = G_lds[pl][64 + lane] * r;
      float m = wave_max(lg);
      float e = expf(lg - m);
      float ssum = wave_sum(e);
      float a = e / ssum;
      float rn2 = wave_sum(a * a * (x2 - 2.f * dt + c2));
      float wf = 1.0f / fmaxf(sqrtf(rn2), FEPS);
      float wval = a * wf;
      s_acc += wval;
      w2_lds[lane][pl] = wval * r;
    }
  }
  sp_lds[wid][lane] = s_acc;
  __syncthreads();
  if (t < 64) {
    float s = 0.f;
#pragma unroll
    for (int g = 0; g < 16; ++g) s += sp_lds[g][t];
    Spart[((size_t)pblk * N_ + n) * 64 + t] = s;
  }
  // w2 writeout: t -> k = t>>4, q = t&15: float4 at p0+q*4
  {
    int k = t >> 4, q = t & 15;
    int p = p0 + q * 4;
    if (p + 3 < P_) {
      float4 v = *(const float4*)&w2_lds[k][q * 4];
      *(float4*)&w2[((size_t)n * K_ + k) * P_ + p] = v;
    }
  }
}

// vpart[s][n][k][c] = sum_{p in slice s} w2[n,k,p]*x[n,c,p]
// grid (4 c-tiles, 8 splits, 8 n) = 256 blocks, 4 p-chunks each.
__global__ __launch_bounds__(256) void k_gemm2(const float* __restrict__ x,
                                               const float* __restrict__ w2,
                                               float* __restrict__ vpart) {
  __shared__ float WsT[32][68];
  __shared__ float XsT[32][68];
  int n = blockIdx.z, s = blockIdx.y;
  int c0 = blockIdx.x * 64;
  int t = threadIdx.x;
  int tx = t & 15, ty = t >> 4;
  float acc[4][4] = {};
  const float* wb = w2 + (size_t)n * K_ * P_;
  const float* xb = x + (size_t)n * C_ * P_;
  int pbase = s * 98;
  for (int q = 0; q < 98; q += 32) {
    int r = t >> 5, pc = t & 31;
    bool ok = (q + pc) < 98;
    int p = pbase + q + pc;
#pragma unroll
    for (int i = 0; i < 8; ++i) {
      int row = r + i * 8;
      WsT[pc][row] = ok ? wb[(size_t)row * P_ + p] : 0.f;
      XsT[pc][row] = ok ? xb[(size_t)(c0 + row) * P_ + p] : 0.f;
    }
    __syncthreads();
#pragma unroll
    for (int pp = 0; pp < 32; ++pp) {
      float4 a = *(const float4*)&WsT[pp][ty * 4];
      float4 bv = *(const float4*)&XsT[pp][tx * 4];
      float av[4] = {a.x, a.y, a.z, a.w};
      float bb[4] = {bv.x, bv.y, bv.z, bv.w};
#pragma unroll
      for (int i = 0; i < 4; ++i)
#pragma unroll
        for (int j = 0; j < 4; ++j) acc[i][j] += av[i] * bb[j];
    }
    __syncthreads();
  }
  float* vb = vpart + (size_t)(s * N_ + n) * K_ * C_;
#pragma unroll
  for (int i = 0; i < 4; ++i)
#pragma unroll
    for (int j = 0; j < 4; ++j)
      vb[(size_t)(ty * 4 + i) * C_ + c0 + tx * 4 + j] = acc[i][j];
}

// vladn[n,k,c] = (sum_s vpart - cent*sum_s Spart) / max(||.||_c, eps). grid 512
__global__ __launch_bounds__(256) void k_vladnorm(const float* __restrict__ vpart,
                                                  const float* __restrict__ cent,
                                                  const float* __restrict__ Spart,
                                                  float* __restrict__ vladn) {
  __shared__ float red[4];
  int b = blockIdx.x;
  int n = b >> 6, k = b & 63;
  int c = threadIdx.x;
  float Sb = 0.f;
#pragma unroll
  for (int s = 0; s < PBLK; ++s) Sb += Spart[((size_t)s * N_ + n) * 64 + k];
  float val = 0.f;
#pragma unroll
  for (int s = 0; s < 8; ++s) val += vpart[(size_t)(s * 512 + b) * C_ + c];
  val -= cent[(size_t)k * C_ + c] * Sb;
  float ss = wave_sum(val * val);
  int wv = threadIdx.x >> 6, lane = threadIdx.x & 63;
  if (lane == 0) red[wv] = ss;
  __syncthreads();
  float tot = red[0] + red[1] + red[2] + red[3];
  float inv = 1.0f / fmaxf(sqrtf(tot), FEPS);
  vladn[(size_t)b * C_ + c] = val * inv;
}

// BatchNorm over n (biased var) + bn affine; per-block partial ssq into nrmpart.
__global__ __launch_bounds__(256) void k_bn(const float* __restrict__ vladn,
                                            const float* __restrict__ bnw,
                                            const float* __restrict__ bnb,
                                            float* __restrict__ ybuf,
                                            float* __restrict__ nrmpart) {
  __shared__ float red[4][8];
  int f = blockIdx.x * 256 + threadIdx.x;
  float v[N_];
  float s = 0.f;
#pragma unroll
  for (int n = 0; n < N_; ++n) { v[n] = vladn[(size_t)n * F_ + f]; s += v[n]; }
  float mean = s * (1.0f / N_);
  float s2 = 0.f;
#pragma unroll
  for (int n = 0; n < N_; ++n) { float d = v[n] - mean; s2 += d * d; }
  float var = s2 * (1.0f / N_);
  float sc = bnw[f] / sqrtf(var + BNEPS);
  float bb = bnb[f];
  float y[N_];
#pragma unroll
  for (int n = 0; n < N_; ++n) {
    y[n] = (v[n] - mean) * sc + bb;
    ybuf[(size_t)n * F_ + f] = y[n];
  }
  int wv = threadIdx.x >> 6, lane = threadIdx.x & 63;
#pragma unroll
  for (int n = 0; n < N_; ++n) {
    float q = wave_sum(y[n] * y[n]);
    if (lane == 0) red[wv][n] = q;
  }
  __syncthreads();
  if (threadIdx.x < N_) {
    int n = threadIdx.x;
    nrmpart[n * 64 + blockIdx.x] = red[0][n] + red[1][n] + red[2][n] + red[3][n];
  }
}

// out = y / max(||y_n||, eps). grid 512.
__global__ __launch_bounds__(256) void k_final(const float* __restrict__ ybuf,
                                               const float* __restrict__ nrmpart,
                                               float* __restrict__ out) {
  int idx = blockIdx.x * 256 + threadIdx.x;
  int n = idx >> 14;
  float tot = 0.f;
#pragma unroll
  for (int b = 0; b < 64; ++b) tot += nrmpart[n * 64 + b];
  float inv = 1.0f / fmaxf(sqrtf(tot), FEPS);
  out[idx] = ybuf[idx] * inv;
}

extern "C" void kernel_launch(void* const* d_in, const int* in_sizes, int n_in,
                              void* d_out, int out_size, void* d_ws, size_t ws_size,
                              hipStream_t stream) {
  const float* x = (const float*)d_in[0];
  const float* convw = (const float*)d_in[1];
  const float* cent = (const float*)d_in[2];
  const float* bnw = (const float*)d_in[3];
  const float* bnb = (const float*)d_in[4];
  float* out = (float*)d_out;
  float* ws = (float*)d_ws;

  float* Spart = ws;                // 13*8*64 = 6656
  float* nrmpart = ws + 6656;       // 512
  float* w2 = ws + 7168;            // 8*64*784 = 401408
  float* vpart = ws + 408576;       // 8*512*256 = 1048576
  float* vladn = ws + 1457152;      // 131072
  float* ybuf = ws + 1588224;       // 131072  (end ~6.9MB)

  k_fused1<<<dim3(PBLK, N_), 1024, 0, stream>>>(x, convw, cent, w2, Spart);
  k_gemm2<<<dim3(4, 8, 8), 256, 0, stream>>>(x, w2, vpart);
  k_vladnorm<<<512, 256, 0, stream>>>(vpart, cent, Spart, vladn);
  k_bn<<<64, 256, 0, stream>>>(vladn, bnw, bnb, ybuf, nrmpart);
  k_final<<<512, 256, 0, stream>>>(ybuf, nrmpart, out);
}